// Round 1
// baseline (480.365 us; speedup 1.0000x reference)
//
#include <hip/hip_runtime.h>
#include <hip/hip_fp16.h>
#include <math.h>

typedef _Float16 half_t;
typedef __attribute__((ext_vector_type(8))) _Float16 f16x8;  // MFMA A/B frag (4 VGPR)
typedef __attribute__((ext_vector_type(4))) float   f32x4;   // MFMA C/D frag
typedef __attribute__((ext_vector_type(4))) float   float4v;

#define IN_F   1536
#define HID    640
#define OUT_F  10
#define NBATCH 65536

// ---------- helpers ----------

// LDS bank swizzle for row-major [128][32] f16 tiles (row = 64B).
// addr byte = (row*64 + kq*16) ^ ((row&7)<<4): rows 0..7 hit distinct bank
// quads {0,20,8,28,16,4,24,12}, rows 8..15 repeat -> 2-way (free, m136).
__device__ __forceinline__ int swz(int row, int kq) {
    int a = (row << 6) | (kq << 4);
    return a ^ ((row & 7) << 4);
}

__device__ __forceinline__ void gll16(const void* g, const void* l) {
    __builtin_amdgcn_global_load_lds(
        (const __attribute__((address_space(1))) unsigned*)g,
        (__attribute__((address_space(3))) unsigned*)l, 16, 0, 0);
}

__device__ __forceinline__ float gelu_exact(float z) {
    return 0.5f * z * (1.0f + erff(z * 0.70710678118654752f));
}

// ---------- prep: mask dtype detection + masked weight build ----------

__global__ void k_init_flags(int* flags) { flags[0] = 0; flags[1] = 0; }

// Classify mask buffer by scanning first nDwords dwords (safe under all layouts):
// flags[1] (weird dword, not in {0,1,0x3F800000}) -> packed bool/int8 bytes
// flags[0] (saw 0x3F800000) -> float32 0/1
// neither -> int32 0/1
__global__ void k_detect(const unsigned* __restrict__ m, int nDwords, int* flags) {
    int f = 0, g = 0;
    for (int i = blockIdx.x * blockDim.x + threadIdx.x; i < nDwords;
         i += gridDim.x * blockDim.x) {
        unsigned d = m[i];
        f |= (d == 0x3F800000u);
        g |= (d != 0u) & (d != 1u) & (d != 0x3F800000u);
    }
    if (f) atomicOr(&flags[0], 1);
    if (g) atomicOr(&flags[1], 1);
}

template <typename OutT>
__global__ void k_mask(const float* __restrict__ W, const void* __restrict__ mask,
                       OutT* __restrict__ out, int n, const int* __restrict__ flags) {
    const int isB = flags[1], isF = flags[0];
    for (int i = blockIdx.x * blockDim.x + threadIdx.x; i < n;
         i += gridDim.x * blockDim.x) {
        bool mv;
        if (isB)      mv = ((const unsigned char*)mask)[i] != 0;
        else if (isF) mv = ((const float*)mask)[i] != 0.0f;
        else          mv = ((const int*)mask)[i] != 0;
        out[i] = mv ? (OutT)W[i] : (OutT)0.0f;
    }
}

// ---------- fused GEMM (+ exact GELU) ----------
// C[m][n] = gelu( sum_k A[m][k] * W[n][k] ), C written as f16 [NBATCH][HID].
// 128x128 tile, BK=32, 256 threads = 4 waves (2x2 of 64x64), 16x16x32 f16 MFMA.
// CVT_A: A is f32 in global, reg-staged + converted to f16 (layer 1).
// else : A is f16 in global, staged via global_load_lds (layer 2).
template <int K, bool CVT_A>
__global__ __launch_bounds__(256, 2) void gemm_gelu_kernel(
    const void* __restrict__ Ain, const half_t* __restrict__ Bw,
    half_t* __restrict__ Cout) {
    constexpr int NK = K / 32;
    // [buf][ A 8KB | B 8KB ] x2
    __shared__ __align__(16) char lds[32768];

    const int t    = threadIdx.x;
    const int lane = t & 63;
    const int wid  = t >> 6;
    const int wr   = wid >> 1, wc = wid & 1;
    const int bid  = blockIdx.x;
    const int mb   = bid / 5, nbk = bid - mb * 5;   // n-fastest: 5 blocks share x panel
    const long mBase = (long)mb * 128;
    const int  n0    = nbk * 128;

    // ds_read fragment addresses (per-thread constant, swizzled)
    int rdA[4], rdB[4];
    {
        const int kq = lane >> 4;
        const int r  = lane & 15;
#pragma unroll
        for (int m = 0; m < 4; ++m) rdA[m] = swz(wr * 64 + m * 16 + r, kq);
#pragma unroll
        for (int n = 0; n < 4; ++n) rdB[n] = 8192 + swz(wc * 64 + n * 16 + r, kq);
    }

    // Inverse swizzle for global_load_lds staging: linear dest o = t*16 holds
    // element (rowS, kqS). o bits: o4=kq0^row0 o5=kq1^row1 o6=row0^row2 o7..=row1..
    int rowS, kqS;
    {
        const int o    = t * 16;
        const int row0 = ((o >> 6) & 1) ^ ((o >> 8) & 1);
        rowS           = ((o >> 7) << 1) | row0;
        kqS            = ((o >> 4) & 3) ^ (rowS & 3);
    }
    const half_t* srcB0 = Bw + (size_t)(n0 + rowS) * K + kqS * 8;
    const half_t* srcB1 = srcB0 + (size_t)64 * K;   // second issue: dest +4096 = row+64

    const float*  srcAf0 = nullptr; const float*  srcAf1 = nullptr;
    const half_t* srcAh0 = nullptr; const half_t* srcAh1 = nullptr;
    int wA0 = 0;
    if constexpr (CVT_A) {
        const int rowA = t >> 2, kqA = t & 3;   // thread -> (row, quad); +64 row for 2nd
        srcAf0 = (const float*)Ain + (size_t)(mBase + rowA) * K + kqA * 8;
        srcAf1 = srcAf0 + (size_t)64 * K;
        wA0    = swz(rowA, kqA);
    } else {
        srcAh0 = (const half_t*)Ain + (size_t)(mBase + rowS) * K + kqS * 8;
        srcAh1 = srcAh0 + (size_t)64 * K;
    }

    // prologue: stage k-step 0 into buf 0
    {
        gll16(srcB0, &lds[8192 + t * 16]);
        gll16(srcB1, &lds[8192 + 4096 + t * 16]);
        if constexpr (CVT_A) {
            float4v a0 = *(const float4v*)(srcAf0);
            float4v a1 = *(const float4v*)(srcAf0 + 4);
            float4v a2 = *(const float4v*)(srcAf1);
            float4v a3 = *(const float4v*)(srcAf1 + 4);
            f16x8 h0, h1v;
#pragma unroll
            for (int i = 0; i < 4; ++i) {
                h0[i] = (half_t)a0[i]; h0[i + 4] = (half_t)a1[i];
                h1v[i] = (half_t)a2[i]; h1v[i + 4] = (half_t)a3[i];
            }
            *(f16x8*)(&lds[wA0])        = h0;
            *(f16x8*)(&lds[wA0 + 4096]) = h1v;
        } else {
            gll16(srcAh0, &lds[t * 16]);
            gll16(srcAh1, &lds[4096 + t * 16]);
        }
    }
    __syncthreads();

    f32x4 acc[4][4];
#pragma unroll
    for (int m = 0; m < 4; ++m)
#pragma unroll
        for (int n = 0; n < 4; ++n) {
            f32x4 z = {0.f, 0.f, 0.f, 0.f};
            acc[m][n] = z;
        }

    int buf = 0;
    for (int ks = 0; ks < NK; ++ks) {
        const int  nbuf    = buf ^ 1;
        const int  nb_base = nbuf * 16384;
        const bool hasNext = (ks + 1) < NK;
        float4v a0, a1, a2, a3;
        if (hasNext) {   // issue next-tile loads BEFORE compute (latency hides under MFMA)
            const size_t koff = (size_t)(ks + 1) * 32;
            gll16(srcB0 + koff, &lds[nb_base + 8192 + t * 16]);
            gll16(srcB1 + koff, &lds[nb_base + 8192 + 4096 + t * 16]);
            if constexpr (CVT_A) {
                a0 = *(const float4v*)(srcAf0 + koff);
                a1 = *(const float4v*)(srcAf0 + koff + 4);
                a2 = *(const float4v*)(srcAf1 + koff);
                a3 = *(const float4v*)(srcAf1 + koff + 4);
            } else {
                gll16(srcAh0 + koff, &lds[nb_base + t * 16]);
                gll16(srcAh1 + koff, &lds[nb_base + 4096 + t * 16]);
            }
        }
        // compute current buffer
        {
            const int cb = buf * 16384;
            f16x8 av[4], bv[4];
#pragma unroll
            for (int m = 0; m < 4; ++m) av[m] = *(const f16x8*)(&lds[cb + rdA[m]]);
#pragma unroll
            for (int n = 0; n < 4; ++n) bv[n] = *(const f16x8*)(&lds[cb + rdB[n]]);
#pragma unroll
            for (int m = 0; m < 4; ++m)
#pragma unroll
                for (int n = 0; n < 4; ++n)
                    acc[m][n] = __builtin_amdgcn_mfma_f32_16x16x32_f16(
                        av[m], bv[n], acc[m][n], 0, 0, 0);
        }
        if (hasNext) {
            if constexpr (CVT_A) {   // write-late half of the async stage split
                f16x8 h0, h1v;
#pragma unroll
                for (int i = 0; i < 4; ++i) {
                    h0[i] = (half_t)a0[i]; h0[i + 4] = (half_t)a1[i];
                    h1v[i] = (half_t)a2[i]; h1v[i + 4] = (half_t)a3[i];
                }
                *(f16x8*)(&lds[nb_base + wA0])        = h0;
                *(f16x8*)(&lds[nb_base + wA0 + 4096]) = h1v;
            }
        }
        __syncthreads();   // drains vmcnt (gll) + lgkm (ds_write); next buf ready
        buf = nbuf;
    }

    // epilogue: C/D frag is col=lane&15, row=(lane>>4)*4+j  (m89-verified mapping)
    const int crow0 = (lane >> 4) * 4;
    const int ccol  = lane & 15;
#pragma unroll
    for (int m = 0; m < 4; ++m)
#pragma unroll
        for (int n = 0; n < 4; ++n)
#pragma unroll
            for (int j = 0; j < 4; ++j) {
                const long row = mBase + wr * 64 + m * 16 + crow0 + j;
                const int  col = n0 + wc * 64 + n * 16 + ccol;
                Cout[row * HID + col] = (half_t)gelu_exact(acc[m][n][j]);
            }
}

// ---------- layer 3: out[b][o] = sum_k h2[b][k] * W3m[o][k], K=640, O=10 ----------
// One wave per row; W3m held in registers (static indices only, rule #20).
__global__ __launch_bounds__(256) void layer3_kernel(
    const half_t* __restrict__ h2, const float* __restrict__ W3m,
    float* __restrict__ out) {
    const int t = threadIdx.x, lane = t & 63, w = t >> 6;
    float w3r[OUT_F][10];
#pragma unroll
    for (int o = 0; o < OUT_F; ++o)
#pragma unroll
        for (int j = 0; j < 10; ++j)
            w3r[o][j] = W3m[o * HID + j * 64 + lane];

    for (long row = (long)blockIdx.x * 4 + w; row < NBATCH; row += (long)gridDim.x * 4) {
        float acc[OUT_F];
#pragma unroll
        for (int o = 0; o < OUT_F; ++o) acc[o] = 0.f;
        const half_t* hr = h2 + row * HID;
#pragma unroll
        for (int j = 0; j < 10; ++j) {
            const float h = (float)hr[j * 64 + lane];
#pragma unroll
            for (int o = 0; o < OUT_F; ++o) acc[o] += h * w3r[o][j];
        }
#pragma unroll
        for (int o = 0; o < OUT_F; ++o) {
            float v = acc[o];
#pragma unroll
            for (int off = 32; off >= 1; off >>= 1) v += __shfl_xor(v, off);
            if (lane == o) out[row * OUT_F + o] = v;
        }
    }
}

// ---------- launch ----------

extern "C" void kernel_launch(void* const* d_in, const int* in_sizes, int n_in,
                              void* d_out, int out_size, void* d_ws, size_t ws_size,
                              hipStream_t stream) {
    const float* x  = (const float*)d_in[0];
    const float* W1 = (const float*)d_in[1];
    const float* W2 = (const float*)d_in[2];
    const float* W3 = (const float*)d_in[3];
    const void*  m1 = d_in[4];
    const void*  m2 = d_in[5];
    const void*  m3 = d_in[6];
    float* out = (float*)d_out;

    char* ws = (char*)d_ws;
    // ws layout (256B aligned): flags | W1h f16 | W2h f16 | W3m f32 | h1 f16 | h2 f16
    int*    flags = (int*)ws;
    half_t* W1h = (half_t*)(ws + 256);
    half_t* W2h = (half_t*)(ws + 256 + 1966080);
    float*  W3m = (float*)(ws + 256 + 1966080 + 819200);
    half_t* h1  = (half_t*)(ws + 256 + 1966080 + 819200 + 25600);
    half_t* h2  = (half_t*)((char*)h1 + (size_t)NBATCH * HID * 2);
    // total ~162.7 MB

    k_init_flags<<<1, 1, 0, stream>>>(flags);
    k_detect<<<480, 256, 0, stream>>>((const unsigned*)m1, (HID * IN_F) / 4, flags);
    k_mask<half_t><<<1024, 256, 0, stream>>>(W1, m1, W1h, HID * IN_F, flags);
    k_mask<half_t><<<512, 256, 0, stream>>>(W2, m2, W2h, HID * HID, flags);
    k_mask<float><<<32, 256, 0, stream>>>(W3, m3, W3m, OUT_F * HID, flags);

    gemm_gelu_kernel<IN_F, true><<<512 * 5, 256, 0, stream>>>((const void*)x, W1h, h1);
    gemm_gelu_kernel<HID, false><<<512 * 5, 256, 0, stream>>>((const void*)h1, W2h, h2);
    layer3_kernel<<<2048, 256, 0, stream>>>(h2, W3m, out);
}

// Round 2
// 408.194 us; speedup vs baseline: 1.1768x; 1.1768x over previous
//
#include <hip/hip_runtime.h>
#include <hip/hip_fp16.h>
#include <math.h>

typedef _Float16 half_t;
typedef __attribute__((ext_vector_type(8))) _Float16 f16x8;  // MFMA A/B frag (4 VGPR)
typedef __attribute__((ext_vector_type(4))) float   f32x4;   // MFMA C/D frag
typedef __attribute__((ext_vector_type(4))) float   float4v;

#define IN_F   1536
#define HID    640
#define OUT_F  10
#define NBATCH 65536

// ---------- helpers ----------

// LDS bank swizzle for row-major [128][32] f16 tiles (row = 64B).
// byte = (row*64 + kq*16) ^ ((row&7)<<4): 2-way max (free, m136).
__device__ __forceinline__ int swz(int row, int kq) {
    int a = (row << 6) | (kq << 4);
    return a ^ ((row & 7) << 4);
}

__device__ __forceinline__ void gll16(const void* g, const void* l) {
    __builtin_amdgcn_global_load_lds(
        (const __attribute__((address_space(1))) unsigned*)g,
        (__attribute__((address_space(3))) unsigned*)l, 16, 0, 0);
}

// exact-GELU via A&S 7.1.26 erf poly (|eps|<=1.5e-7, noise vs f16 rounding)
__device__ __forceinline__ float gelu_fast(float z) {
    float x  = 0.70710678118654752f * z;
    float ax = fabsf(x);
    float t  = 1.0f / (1.0f + 0.3275911f * ax);
    float p  = t * (0.254829592f +
               t * (-0.284496736f +
               t * (1.421413741f +
               t * (-1.453152027f +
               t * 1.061405429f))));
    float e  = __expf(-ax * ax);
    float er = 1.0f - p * e;         // erf(|x|)
    er = (x < 0.0f) ? -er : er;
    return 0.5f * z * (1.0f + er);
}

// ---------- prep: mask dtype detection + masked weight build ----------

__global__ void k_init_flags(int* flags) { flags[0] = 0; flags[1] = 0; }

__global__ void k_detect(const unsigned* __restrict__ m, int nDwords, int* flags) {
    int f = 0, g = 0;
    for (int i = blockIdx.x * blockDim.x + threadIdx.x; i < nDwords;
         i += gridDim.x * blockDim.x) {
        unsigned d = m[i];
        f |= (d == 0x3F800000u);
        g |= (d != 0u) & (d != 1u) & (d != 0x3F800000u);
    }
    if (f) atomicOr(&flags[0], 1);
    if (g) atomicOr(&flags[1], 1);
}

template <typename OutT>
__global__ void k_mask(const float* __restrict__ W, const void* __restrict__ mask,
                       OutT* __restrict__ out, int n, const int* __restrict__ flags) {
    const int isB = flags[1], isF = flags[0];
    for (int i = blockIdx.x * blockDim.x + threadIdx.x; i < n;
         i += gridDim.x * blockDim.x) {
        bool mv;
        if (isB)      mv = ((const unsigned char*)mask)[i] != 0;
        else if (isF) mv = ((const float*)mask)[i] != 0.0f;
        else          mv = ((const int*)mask)[i] != 0;
        out[i] = mv ? (OutT)W[i] : (OutT)0.0f;
    }
}

// ---------- fused GEMM (+ exact GELU), counted-vmcnt depth-2 pipeline ----------
// C[m][n] = gelu( sum_k A[m][k] * W[n][k] ), C written f16 [NBATCH][HID].
// 128x128 tile, BK=32, 4 waves (2x2 of 64x64), 16x16x32 f16 MFMA.
// CVT_A: A f32 in global, reg-staged (T14 split, depth-2) + cvt to f16.
// else : A f16 in global, staged via global_load_lds (depth-2).
// Ring protocol per K-step ks (buffers buf[ks&1]):
//   vmcnt(TOP)            -> own STAGE(ks) complete   (TOP = in-flight ks+1/ks+2 ops)
//   lgkmcnt(0)            -> own A ds_writes (CVT_A) complete
//   s_barrier             -> buffer ks READY for all waves
//   ds_read 8 frags; lgkmcnt(0); sched_barrier(0)
//   s_barrier             -> buffer ks CONSUMED by all waves
//   STAGE(ks+2) -> buf[ks&1]; [CVT_A: vmcnt(MID); cvt+ds_write tile ks+1]
//   16 x MFMA
template <int K, bool CVT_A>
__global__ __launch_bounds__(256, 2) void gemm_gelu(
    const void* __restrict__ Ain, const half_t* __restrict__ Bw,
    half_t* __restrict__ Cout) {
    constexpr int NK = K / 32;                     // even (48 or 20)
    __shared__ __align__(16) char lds[32768];      // [buf][A 8KB | B 8KB] x2

    const int t    = threadIdx.x;
    const int lane = t & 63;
    const int wid  = t >> 6;
    const int wr   = wid >> 1, wc = wid & 1;

    // T1: XCD-bijective swizzle (nwg = 2560 = 8*320); n-fastest so the 5
    // n-blocks sharing an x panel are contiguous on one XCD's L2.
    const int q       = (int)gridDim.x >> 3;
    const int logical = ((int)blockIdx.x & 7) * q + ((int)blockIdx.x >> 3);
    const int mb  = logical / 5, nbk = logical - mb * 5;
    const long mBase = (long)mb * 128;
    const int  n0    = nbk * 128;

    // ds_read fragment addresses (per-thread constant, swizzled)
    int rdA[4], rdB[4];
    {
        const int kq = lane >> 4;
        const int r  = lane & 15;
#pragma unroll
        for (int m = 0; m < 4; ++m) rdA[m] = swz(wr * 64 + m * 16 + r, kq);
#pragma unroll
        for (int n = 0; n < 4; ++n) rdB[n] = 8192 + swz(wc * 64 + n * 16 + r, kq);
    }

    // Inverse swizzle for global_load_lds staging (linear dest o = t*16).
    int rowS, kqS;
    {
        const int o    = t * 16;
        const int row0 = ((o >> 6) & 1) ^ ((o >> 8) & 1);
        rowS           = ((o >> 7) << 1) | row0;
        kqS            = ((o >> 4) & 3) ^ (rowS & 3);
    }
    const half_t* srcB0 = Bw + (size_t)(n0 + rowS) * K + kqS * 8;
    const half_t* srcB1 = srcB0 + (size_t)64 * K;

    const float*  srcAf0 = nullptr; const float*  srcAf1 = nullptr;
    const half_t* srcAh0 = nullptr; const half_t* srcAh1 = nullptr;
    int wA0 = 0;
    if constexpr (CVT_A) {
        const int rowA = t >> 2, kqA = t & 3;
        srcAf0 = (const float*)Ain + (size_t)(mBase + rowA) * K + kqA * 8;
        srcAf1 = srcAf0 + (size_t)64 * K;
        wA0    = swz(rowA, kqA);
    } else {
        srcAh0 = (const half_t*)Ain + (size_t)(mBase + rowS) * K + kqS * 8;
        srcAh1 = srcAh0 + (size_t)64 * K;
    }

    // staging primitives
    auto BW = [&](int k, int bufb) {
        const size_t koff = (size_t)k * 32;
        gll16(srcB0 + koff, &lds[bufb + 8192 + t * 16]);
        gll16(srcB1 + koff, &lds[bufb + 8192 + 4096 + t * 16]);
    };
    auto AHW = [&](int k, int bufb) {   // A via gll16 (non-CVT path)
        const size_t koff = (size_t)k * 32;
        gll16(srcAh0 + koff, &lds[bufb + t * 16]);
        gll16(srcAh1 + koff, &lds[bufb + 4096 + t * 16]);
    };
    auto GL = [&](int k, float4v (&s)[4]) {   // A f32 -> regs (issue-early)
        const size_t koff = (size_t)k * 32;
        s[0] = *(const float4v*)(srcAf0 + koff);
        s[1] = *(const float4v*)(srcAf0 + koff + 4);
        s[2] = *(const float4v*)(srcAf1 + koff);
        s[3] = *(const float4v*)(srcAf1 + koff + 4);
    };
    auto AW = [&](const float4v (&s)[4], int bufb) {   // cvt + ds_write (write-late)
        f16x8 h0, h1v;
#pragma unroll
        for (int i = 0; i < 4; ++i) {
            h0[i]  = (half_t)s[0][i]; h0[i + 4]  = (half_t)s[1][i];
            h1v[i] = (half_t)s[2][i]; h1v[i + 4] = (half_t)s[3][i];
        }
        *(f16x8*)(&lds[bufb + wA0])        = h0;
        *(f16x8*)(&lds[bufb + wA0 + 4096]) = h1v;
    };

    f32x4 acc[4][4];
#pragma unroll
    for (int m = 0; m < 4; ++m)
#pragma unroll
        for (int n = 0; n < 4; ++n) {
            f32x4 z = {0.f, 0.f, 0.f, 0.f};
            acc[m][n] = z;
        }

    float4v setE[4], setO[4];

    // prologue: stage tiles 0 and 1 (depth-2)
    if constexpr (CVT_A) {
        GL(0, setE); BW(0, 0);
        GL(1, setO); BW(1, 16384);
        asm volatile("s_waitcnt vmcnt(8)" ::: "memory");   // GL(0) done
        AW(setE, 0);
    } else {
        AHW(0, 0);      BW(0, 0);
        AHW(1, 16384);  BW(1, 16384);
    }

    auto iter = [&](int ks, float4v (&glset)[4], float4v (&awset)[4]) {
        const int cb = (ks & 1) * 16384;   // buffer holding tile ks
        const int ob = cb ^ 16384;         // buffer holding tile ks+1
        // --- ready phase ---
        if (ks + 1 < NK) {
            if constexpr (CVT_A) asm volatile("s_waitcnt vmcnt(6)" ::: "memory");
            else                 asm volatile("s_waitcnt vmcnt(4)" ::: "memory");
        } else {
            asm volatile("s_waitcnt vmcnt(0)" ::: "memory");
        }
        asm volatile("s_waitcnt lgkmcnt(0)" ::: "memory");
        asm volatile("s_barrier" ::: "memory");            // buffer ks ready
        f16x8 av[4], bv[4];
#pragma unroll
        for (int m = 0; m < 4; ++m) av[m] = *(const f16x8*)(&lds[cb + rdA[m]]);
#pragma unroll
        for (int n = 0; n < 4; ++n) bv[n] = *(const f16x8*)(&lds[cb + rdB[n]]);
        asm volatile("s_waitcnt lgkmcnt(0)" ::: "memory"); // own reads landed
        __builtin_amdgcn_sched_barrier(0);                 // pin reads above (rule 18)
        asm volatile("s_barrier" ::: "memory");            // buffer ks consumed
        // --- prefetch phase (never drained; covers ~2 K-steps of MFMA) ---
        if (ks + 2 < NK) {
            if constexpr (CVT_A) GL(ks + 2, glset);
            else                 AHW(ks + 2, cb);
            BW(ks + 2, cb);
        }
        if constexpr (CVT_A) {
            if (ks + 1 < NK) {
                if (ks + 2 < NK) asm volatile("s_waitcnt vmcnt(8)" ::: "memory");
                else             asm volatile("s_waitcnt vmcnt(2)" ::: "memory");
                AW(awset, ob);   // write-late: tile ks+1 into other buffer
            }
        }
        // --- compute ---
#pragma unroll
        for (int m = 0; m < 4; ++m)
#pragma unroll
            for (int n = 0; n < 4; ++n)
                acc[m][n] = __builtin_amdgcn_mfma_f32_16x16x32_f16(
                    av[m], bv[n], acc[m][n], 0, 0, 0);
    };

    // unroll-by-2 so the two in-flight A reg-sets are statically indexed (rule 20)
    for (int ks = 0; ks < NK; ks += 2) {
        iter(ks,     setE, setO);   // GL(ks+2)->setE, AW(ks+1)<-setO
        iter(ks + 1, setO, setE);   // GL(ks+3)->setO, AW(ks+2)<-setE
    }

    // epilogue: C/D frag col=lane&15, row=(lane>>4)*4+j (m89-verified)
    const int crow0 = (lane >> 4) * 4;
    const int ccol  = lane & 15;
#pragma unroll
    for (int m = 0; m < 4; ++m)
#pragma unroll
        for (int n = 0; n < 4; ++n)
#pragma unroll
            for (int j = 0; j < 4; ++j) {
                const long row = mBase + wr * 64 + m * 16 + crow0 + j;
                const int  col = n0 + wc * 64 + n * 16 + ccol;
                Cout[row * HID + col] = (half_t)gelu_fast(acc[m][n][j]);
            }
}

// ---------- layer 3: out[b][o] = sum_k h2[b][k] * W3m[o][k], K=640, O=10 ----------
__global__ __launch_bounds__(256) void layer3_kernel(
    const half_t* __restrict__ h2, const float* __restrict__ W3m,
    float* __restrict__ out) {
    const int t = threadIdx.x, lane = t & 63, w = t >> 6;
    float w3r[OUT_F][10];
#pragma unroll
    for (int o = 0; o < OUT_F; ++o)
#pragma unroll
        for (int j = 0; j < 10; ++j)
            w3r[o][j] = W3m[o * HID + j * 64 + lane];

    for (long row = (long)blockIdx.x * 4 + w; row < NBATCH; row += (long)gridDim.x * 4) {
        float acc[OUT_F];
#pragma unroll
        for (int o = 0; o < OUT_F; ++o) acc[o] = 0.f;
        const half_t* hr = h2 + row * HID;
#pragma unroll
        for (int j = 0; j < 10; ++j) {
            const float h = (float)hr[j * 64 + lane];
#pragma unroll
            for (int o = 0; o < OUT_F; ++o) acc[o] += h * w3r[o][j];
        }
#pragma unroll
        for (int o = 0; o < OUT_F; ++o) {
            float v = acc[o];
#pragma unroll
            for (int off = 32; off >= 1; off >>= 1) v += __shfl_xor(v, off);
            if (lane == o) out[row * OUT_F + o] = v;
        }
    }
}

// ---------- launch ----------

extern "C" void kernel_launch(void* const* d_in, const int* in_sizes, int n_in,
                              void* d_out, int out_size, void* d_ws, size_t ws_size,
                              hipStream_t stream) {
    const float* x  = (const float*)d_in[0];
    const float* W1 = (const float*)d_in[1];
    const float* W2 = (const float*)d_in[2];
    const float* W3 = (const float*)d_in[3];
    const void*  m1 = d_in[4];
    const void*  m2 = d_in[5];
    const void*  m3 = d_in[6];
    float* out = (float*)d_out;

    char* ws = (char*)d_ws;
    int*    flags = (int*)ws;
    half_t* W1h = (half_t*)(ws + 256);
    half_t* W2h = (half_t*)(ws + 256 + 1966080);
    float*  W3m = (float*)(ws + 256 + 1966080 + 819200);
    half_t* h1  = (half_t*)(ws + 256 + 1966080 + 819200 + 25600);
    half_t* h2  = (half_t*)((char*)h1 + (size_t)NBATCH * HID * 2);
    // total ~162.7 MB (fits: round-1 proof)

    k_init_flags<<<1, 1, 0, stream>>>(flags);
    k_detect<<<480, 256, 0, stream>>>((const unsigned*)m1, (HID * IN_F) / 4, flags);
    k_mask<half_t><<<1024, 256, 0, stream>>>(W1, m1, W1h, HID * IN_F, flags);
    k_mask<half_t><<<512, 256, 0, stream>>>(W2, m2, W2h, HID * HID, flags);
    k_mask<float><<<32, 256, 0, stream>>>(W3, m3, W3m, OUT_F * HID, flags);

    gemm_gelu<IN_F, true><<<2560, 256, 0, stream>>>((const void*)x, W1h, h1);
    gemm_gelu<HID, false><<<2560, 256, 0, stream>>>((const void*)h1, W2h, h2);
    layer3_kernel<<<2048, 256, 0, stream>>>(h2, W3m, out);
}

// Round 3
// 383.911 us; speedup vs baseline: 1.2512x; 1.0633x over previous
//
#include <hip/hip_runtime.h>
#include <hip/hip_fp16.h>
#include <math.h>

typedef _Float16 half_t;
typedef __attribute__((ext_vector_type(8))) _Float16 f16x8;  // MFMA A/B frag (4 VGPR)
typedef __attribute__((ext_vector_type(4))) float   f32x4;   // MFMA C/D frag
typedef __attribute__((ext_vector_type(4))) float   float4v;

#define IN_F   1536
#define HID    640
#define OUT_F  10
#define NBATCH 65536

#define SB() __builtin_amdgcn_sched_barrier(0)

// ---------- helpers ----------

// LDS bank swizzle for row-major [128][32] f16 tiles (row = 64B).
// byte = (row*64 + kq*16) ^ ((row&7)<<4): reads 2-way max (free, m136).
__device__ __forceinline__ int swz(int row, int kq) {
    int a = (row << 6) | (kq << 4);
    return a ^ ((row & 7) << 4);
}

__device__ __forceinline__ void gll16(const void* g, const void* l) {
    __builtin_amdgcn_global_load_lds(
        (const __attribute__((address_space(1))) unsigned*)g,
        (__attribute__((address_space(3))) unsigned*)l, 16, 0, 0);
}

// exact-GELU via A&S 7.1.26 erf poly (|eps|<=1.5e-7, noise vs f16 rounding)
__device__ __forceinline__ float gelu_fast(float z) {
    float x  = 0.70710678118654752f * z;
    float ax = fabsf(x);
    float t  = 1.0f / (1.0f + 0.3275911f * ax);
    float p  = t * (0.254829592f +
               t * (-0.284496736f +
               t * (1.421413741f +
               t * (-1.453152027f +
               t * 1.061405429f))));
    float e  = __expf(-ax * ax);
    float er = 1.0f - p * e;         // erf(|x|)
    er = (x < 0.0f) ? -er : er;
    return 0.5f * z * (1.0f + er);
}

// ---------- prep: mask dtype detection + masked weight build ----------

// Classify mask buffer from a 256KB prefix (statistically certain):
// flags[1] (dword not in {0,1,0x3F800000}) -> packed bool/int8 bytes
// flags[0] (saw 0x3F800000) -> float32 0/1 ; neither -> int32 0/1
__global__ void k_detect(const unsigned* __restrict__ m, int nDwords, int* flags) {
    int f = 0, g = 0;
    for (int i = blockIdx.x * blockDim.x + threadIdx.x; i < nDwords;
         i += gridDim.x * blockDim.x) {
        unsigned d = m[i];
        f |= (d == 0x3F800000u);
        g |= (d != 0u) & (d != 1u) & (d != 0x3F800000u);
    }
    if (f) atomicOr(&flags[0], 1);
    if (g) atomicOr(&flags[1], 1);
}

__device__ __forceinline__ bool mask_at(const void* mask, int i, int isB, int isF) {
    if (isB) return ((const unsigned char*)mask)[i] != 0;
    if (isF) return ((const float*)mask)[i] != 0.0f;
    return ((const int*)mask)[i] != 0;
}

__global__ void k_mask_all(const float* __restrict__ W1, const float* __restrict__ W2,
                           const float* __restrict__ W3,
                           const void* __restrict__ m1, const void* __restrict__ m2,
                           const void* __restrict__ m3,
                           half_t* __restrict__ W1h, half_t* __restrict__ W2h,
                           float* __restrict__ W3m, const int* __restrict__ flags) {
    const int isB = flags[1], isF = flags[0];
    const int N1 = HID * IN_F, N2 = HID * HID, N3 = OUT_F * HID;
    const int NT = N1 + N2 + N3;
    for (int i = blockIdx.x * blockDim.x + threadIdx.x; i < NT;
         i += gridDim.x * blockDim.x) {
        if (i < N1) {
            W1h[i] = mask_at(m1, i, isB, isF) ? (half_t)W1[i] : (half_t)0.0f;
        } else if (i < N1 + N2) {
            int j = i - N1;
            W2h[j] = mask_at(m2, j, isB, isF) ? (half_t)W2[j] : (half_t)0.0f;
        } else {
            int j = i - N1 - N2;
            W3m[j] = mask_at(m3, j, isB, isF) ? W3[j] : 0.0f;
        }
    }
}

// ---------- fused GEMM (+ exact GELU), counted-vmcnt pipeline ----------
// C[m][n] = gelu( sum_k A[m][k] * W[n][k] ), C written f16 [NBATCH][HID].
// 128x128 tile, BK=32, 4 waves (2x2 of 64x64), 16x16x32 f16 MFMA.
//
// CVT_A (layer 1): A f32 in global -> depth-3 reg pipeline -> cvt f16 -> ds_write.
//   Steady-state iter ks (entry outstanding, issue order:
//   BW(ks)2, GL(ks+1)4, BW(ks+1)2, GL(ks+2)4 = 12):
//     vmcnt(10)                retire BW(ks)   [issued 2 iters ago]
//     lgkmcnt(0)               own AW(ks) ds_writes done
//     s_barrier                buf[ks&1] READY
//     8x ds_read; lgkmcnt(0); sched_barrier; s_barrier   (CONSUMED)
//     BW(ks+2)->buf[ks&1] | GL(ks+3)->reg set[ks%3]
//     16x MFMA (setprio 1)
//     vmcnt(12)                retire GL(ks+1) [issued 2 iters ago]
//     AW(set[(ks+1)%3]) -> buf[(ks+1)&1]
// non-CVT (layer 2): both operands via global_load_lds, depth-2 (R2-verified).
template <int K, bool CVT_A>
__global__ __launch_bounds__(256, 2) void gemm_gelu(
    const void* __restrict__ Ain, const half_t* __restrict__ Bw,
    half_t* __restrict__ Cout) {
    constexpr int NK = K / 32;
    static_assert(!CVT_A || (NK % 3 == 0 && NK >= 6), "CVT path needs NK%3==0");
    __shared__ __align__(16) char lds[32768];      // [buf][A 8KB | B 8KB] x2

    const int t    = threadIdx.x;
    const int lane = t & 63;
    const int wid  = t >> 6;
    const int wr   = wid >> 1, wc = wid & 1;

    // T1: XCD-bijective swizzle (nwg = 2560 = 8*320); n-fastest so the 5
    // n-blocks sharing an x panel are contiguous on one XCD's L2.
    const int q       = (int)gridDim.x >> 3;
    const int logical = ((int)blockIdx.x & 7) * q + ((int)blockIdx.x >> 3);
    const int mb  = logical / 5, nbk = logical - mb * 5;
    const long mBase = (long)mb * 128;
    const int  n0    = nbk * 128;

    // ds_read fragment addresses (per-thread constant, swizzled)
    int rdA[4], rdB[4];
    {
        const int kq = lane >> 4;
        const int r  = lane & 15;
#pragma unroll
        for (int m = 0; m < 4; ++m) rdA[m] = swz(wr * 64 + m * 16 + r, kq);
#pragma unroll
        for (int n = 0; n < 4; ++n) rdB[n] = 8192 + swz(wc * 64 + n * 16 + r, kq);
    }

    // Inverse swizzle for global_load_lds staging (linear dest o = t*16).
    int rowS, kqS;
    {
        const int o    = t * 16;
        const int row0 = ((o >> 6) & 1) ^ ((o >> 8) & 1);
        rowS           = ((o >> 7) << 1) | row0;
        kqS            = ((o >> 4) & 3) ^ (rowS & 3);
    }
    const half_t* srcB0 = Bw + (size_t)(n0 + rowS) * K + kqS * 8;
    const half_t* srcB1 = srcB0 + (size_t)64 * K;

    const float*  srcAf0 = nullptr; const float*  srcAf1 = nullptr;
    const half_t* srcAh0 = nullptr; const half_t* srcAh1 = nullptr;
    int wA0 = 0;
    if constexpr (CVT_A) {
        const int rowA = t >> 2, kqA = t & 3;
        srcAf0 = (const float*)Ain + (size_t)(mBase + rowA) * K + kqA * 8;
        srcAf1 = srcAf0 + (size_t)64 * K;
        wA0    = swz(rowA, kqA);
    } else {
        srcAh0 = (const half_t*)Ain + (size_t)(mBase + rowS) * K + kqS * 8;
        srcAh1 = srcAh0 + (size_t)64 * K;
    }

    auto BW = [&](int k, int bufb) {
        const size_t koff = (size_t)k * 32;
        gll16(srcB0 + koff, &lds[bufb + 8192 + t * 16]);
        gll16(srcB1 + koff, &lds[bufb + 8192 + 4096 + t * 16]);
    };
    auto AHW = [&](int k, int bufb) {
        const size_t koff = (size_t)k * 32;
        gll16(srcAh0 + koff, &lds[bufb + t * 16]);
        gll16(srcAh1 + koff, &lds[bufb + 4096 + t * 16]);
    };
    auto GL = [&](int k, float4v (&s)[4]) {
        const size_t koff = (size_t)k * 32;
        s[0] = *(const float4v*)(srcAf0 + koff);
        s[1] = *(const float4v*)(srcAf0 + koff + 4);
        s[2] = *(const float4v*)(srcAf1 + koff);
        s[3] = *(const float4v*)(srcAf1 + koff + 4);
    };
    auto AW = [&](const float4v (&s)[4], int bufb) {
        f16x8 h0, h1v;
#pragma unroll
        for (int i = 0; i < 4; ++i) {
            h0[i]  = (half_t)s[0][i]; h0[i + 4]  = (half_t)s[1][i];
            h1v[i] = (half_t)s[2][i]; h1v[i + 4] = (half_t)s[3][i];
        }
        *(f16x8*)(&lds[bufb + wA0])        = h0;
        *(f16x8*)(&lds[bufb + wA0 + 4096]) = h1v;
    };

    f32x4 acc[4][4];
#pragma unroll
    for (int m = 0; m < 4; ++m)
#pragma unroll
        for (int n = 0; n < 4; ++n) {
            f32x4 z = {0.f, 0.f, 0.f, 0.f};
            acc[m][n] = z;
        }

    f16x8 av[4], bv[4];
    auto READS = [&](int cb) {
#pragma unroll
        for (int m = 0; m < 4; ++m) av[m] = *(const f16x8*)(&lds[cb + rdA[m]]);
#pragma unroll
        for (int n = 0; n < 4; ++n) bv[n] = *(const f16x8*)(&lds[cb + rdB[n]]);
        asm volatile("s_waitcnt lgkmcnt(0)" ::: "memory");
        SB();
    };
    auto MFMA = [&]() {
        __builtin_amdgcn_s_setprio(1);
#pragma unroll
        for (int m = 0; m < 4; ++m)
#pragma unroll
            for (int n = 0; n < 4; ++n)
                acc[m][n] = __builtin_amdgcn_mfma_f32_16x16x32_f16(
                    av[m], bv[n], acc[m][n], 0, 0, 0);
        __builtin_amdgcn_s_setprio(0);
        SB();
    };

    if constexpr (CVT_A) {
        float4v s0[4], s1[4], s2[4];
        // prologue: GL depth-3, BW depth-2  (outstanding: 4,2,4,2,4 = 16)
        GL(0, s0); SB(); BW(0, 0); SB();
        GL(1, s1); SB(); BW(1, 16384); SB();
        GL(2, s2); SB();
        asm volatile("s_waitcnt vmcnt(12)" ::: "memory");   // GL(0) done
        AW(s0, 0);

        auto citer = [&](int ks, float4v (&glset)[4], float4v (&awset)[4]) {
            const int cb = (ks & 1) * 16384;
            asm volatile("s_waitcnt vmcnt(10)" ::: "memory");  // BW(ks) done
            asm volatile("s_waitcnt lgkmcnt(0)" ::: "memory"); // AW(ks) writes done
            __builtin_amdgcn_s_barrier();                      // buf ks READY
            READS(cb);
            __builtin_amdgcn_s_barrier();                      // buf ks CONSUMED
            BW(ks + 2, cb); SB();
            GL(ks + 3, glset); SB();
            MFMA();
            asm volatile("s_waitcnt vmcnt(12)" ::: "memory");  // GL(ks+1) done
            AW(awset, cb ^ 16384);
        };
        for (int ks = 0; ks + 3 < NK; ks += 3) {   // full iters: ks = 0 .. NK-4
            citer(ks,     s0, s1);
            citer(ks + 1, s1, s2);
            citer(ks + 2, s2, s0);
        }
        {   // ks = NK-3  (no GL; BW(NK-1) still issued)
            const int cb = ((NK - 3) & 1) * 16384;
            asm volatile("s_waitcnt vmcnt(10)" ::: "memory");
            asm volatile("s_waitcnt lgkmcnt(0)" ::: "memory");
            __builtin_amdgcn_s_barrier();
            READS(cb);
            __builtin_amdgcn_s_barrier();
            BW(NK - 1, cb); SB();
            MFMA();
            asm volatile("s_waitcnt vmcnt(8)" ::: "memory");   // GL(NK-2) done
            AW(s1, cb ^ 16384);
        }
        {   // ks = NK-2  (no issues)
            const int cb = ((NK - 2) & 1) * 16384;
            asm volatile("s_waitcnt vmcnt(6)" ::: "memory");   // BW(NK-2) done
            asm volatile("s_waitcnt lgkmcnt(0)" ::: "memory");
            __builtin_amdgcn_s_barrier();
            READS(cb);
            __builtin_amdgcn_s_barrier();
            MFMA();
            asm volatile("s_waitcnt vmcnt(2)" ::: "memory");   // GL(NK-1) done
            AW(s2, cb ^ 16384);
        }
        {   // ks = NK-1
            const int cb = ((NK - 1) & 1) * 16384;
            asm volatile("s_waitcnt vmcnt(0)" ::: "memory");
            asm volatile("s_waitcnt lgkmcnt(0)" ::: "memory");
            __builtin_amdgcn_s_barrier();
            READS(cb);
            MFMA();
        }
    } else {
        // depth-2, both operands via global_load_lds (R2-verified schedule)
        AHW(0, 0);      SB(); BW(0, 0);      SB();
        AHW(1, 16384);  SB(); BW(1, 16384);  SB();
        for (int ks = 0; ks < NK; ++ks) {
            const int cb = (ks & 1) * 16384;
            if (ks + 1 < NK) asm volatile("s_waitcnt vmcnt(4)" ::: "memory");
            else             asm volatile("s_waitcnt vmcnt(0)" ::: "memory");
            __builtin_amdgcn_s_barrier();
            READS(cb);
            __builtin_amdgcn_s_barrier();
            if (ks + 2 < NK) { AHW(ks + 2, cb); BW(ks + 2, cb); SB(); }
            MFMA();
        }
    }

    // epilogue: C/D frag col=lane&15, row=(lane>>4)*4+j (m89-verified)
    const int crow0 = (lane >> 4) * 4;
    const int ccol  = lane & 15;
#pragma unroll
    for (int m = 0; m < 4; ++m)
#pragma unroll
        for (int n = 0; n < 4; ++n)
#pragma unroll
            for (int j = 0; j < 4; ++j) {
                const long row = mBase + wr * 64 + m * 16 + crow0 + j;
                const int  col = n0 + wc * 64 + n * 16 + ccol;
                Cout[row * HID + col] = (half_t)gelu_fast(acc[m][n][j]);
            }
}

// ---------- layer 3: out[b][o] = sum_k h2[b][k] * W3m[o][k], K=640, O=10 ----------
__global__ __launch_bounds__(256) void layer3_kernel(
    const half_t* __restrict__ h2, const float* __restrict__ W3m,
    float* __restrict__ out) {
    const int t = threadIdx.x, lane = t & 63, w = t >> 6;
    float w3r[OUT_F][10];
#pragma unroll
    for (int o = 0; o < OUT_F; ++o)
#pragma unroll
        for (int j = 0; j < 10; ++j)
            w3r[o][j] = W3m[o * HID + j * 64 + lane];

    for (long row = (long)blockIdx.x * 4 + w; row < NBATCH; row += (long)gridDim.x * 4) {
        float acc[OUT_F];
#pragma unroll
        for (int o = 0; o < OUT_F; ++o) acc[o] = 0.f;
        const half_t* hr = h2 + row * HID;
#pragma unroll
        for (int j = 0; j < 10; ++j) {
            const float h = (float)hr[j * 64 + lane];
#pragma unroll
            for (int o = 0; o < OUT_F; ++o) acc[o] += h * w3r[o][j];
        }
#pragma unroll
        for (int o = 0; o < OUT_F; ++o) {
            float v = acc[o];
#pragma unroll
            for (int off = 32; off >= 1; off >>= 1) v += __shfl_xor(v, off);
            if (lane == o) out[row * OUT_F + o] = v;
        }
    }
}

// ---------- launch ----------

extern "C" void kernel_launch(void* const* d_in, const int* in_sizes, int n_in,
                              void* d_out, int out_size, void* d_ws, size_t ws_size,
                              hipStream_t stream) {
    const float* x  = (const float*)d_in[0];
    const float* W1 = (const float*)d_in[1];
    const float* W2 = (const float*)d_in[2];
    const float* W3 = (const float*)d_in[3];
    const void*  m1 = d_in[4];
    const void*  m2 = d_in[5];
    const void*  m3 = d_in[6];
    float* out = (float*)d_out;

    char* ws = (char*)d_ws;
    int*    flags = (int*)ws;
    half_t* W1h = (half_t*)(ws + 256);
    half_t* W2h = (half_t*)(ws + 256 + 1966080);
    float*  W3m = (float*)(ws + 256 + 1966080 + 819200);
    half_t* h1  = (half_t*)(ws + 256 + 1966080 + 819200 + 25600);
    half_t* h2  = (half_t*)((char*)h1 + (size_t)NBATCH * HID * 2);
    // total ~162.7 MB (fits: round-1 proof)

    hipMemsetAsync(flags, 0, 8, stream);
    k_detect<<<64, 256, 0, stream>>>((const unsigned*)m1, 65536, flags);
    k_mask_all<<<1024, 256, 0, stream>>>(W1, W2, W3, m1, m2, m3, W1h, W2h, W3m, flags);

    gemm_gelu<IN_F, true><<<2560, 256, 0, stream>>>((const void*)x, W1h, h1);
    gemm_gelu<HID, false><<<2560, 256, 0, stream>>>((const void*)h1, W2h, h2);
    layer3_kernel<<<2048, 256, 0, stream>>>(h2, W3m, out);
}